// Round 7
// baseline (1049.923 us; speedup 1.0000x reference)
//
#include <hip/hip_runtime.h>

// i_in[post[s]] += w[s] * (act[pre[s]] > 0);  N_SYN=30M, N_POST=200k, N_SRC=17400.
//
// Evidence: r2=487 (two-phase best), r5 occupancy bump neutral => p1 not
// latency-bound. Two-phase's cost is structural: 92MB pairs round-trip + p2
// histogram + extra dispatches. Direct-atomic 727us was NOT "atomics slow"
// but cross-XCD line ping-pong: ~2000 atomics/64B line on out from 8 XCDs.
//
// This version (r6 resubmit; r6 was an infra failure — only change: replace
// inline-asm hwreg(HW_REG_XCC_ID) with __builtin_amdgcn_s_getreg numeric
// encoding to remove any assembler-name risk):
// Single-phase scatter into 16 REPLICAS keyed by PHYSICAL XCD (id=20).
// Each 800KB replica is touched by one XCD only -> lines stay dirty in that
// XCD's private 4MB L2 -> atomics are L2-local RMW, fire-and-forget.
// Merge: out[g] = sum_k rep[k][g] (12.8MB, cache-resident).
// Full fp32 weights (no truncation) -> absmax should drop 0.125 -> ~1e-5.
// Dispatches: memset(rep) + p0 + p1x + p3 = 4.

typedef int   vint4   __attribute__((ext_vector_type(4)));
typedef float vfloat4 __attribute__((ext_vector_type(4)));
typedef unsigned int uint;

#define NW_MAX 544                    // act bitmask words: ceil(17400/32)
#define REP    16                     // replicas: 8 XCDs x 2 (block parity)
#define P1_BLK 256
#define P1_GRID_CAP 2048              // 8 blocks/CU, grid-stride

// s_getreg_b32 imm encoding: id[5:0] | offset[10:6] | (size-1)[15:11]
// HW_REG_XCC_ID = 20 (gfx940+), offset 0, size 32.
#define GETREG_XCC_ID (20 | (0 << 6) | (31 << 11))

__global__ __launch_bounds__(256) void p0_bitmask(
    const int* __restrict__ act, uint* __restrict__ bits_g, int n_src)
{
    int w  = blockIdx.x * blockDim.x + threadIdx.x;
    int nw = (n_src + 31) >> 5;
    if (w < nw) {
        uint m = 0;
        int base = w << 5;
        #pragma unroll
        for (int j = 0; j < 32; ++j) {
            int s = base + j;
            if (s < n_src && act[s] > 0) m |= (1u << j);
        }
        bits_g[w] = m;
    }
}

__global__ __launch_bounds__(P1_BLK) void p1_scatter_rep(
    const uint* __restrict__ bits_g,
    const vint4* __restrict__ idx4,
    const vfloat4* __restrict__ w4,
    float* __restrict__ rep,          // [REP][n_post], pre-zeroed
    int n_vec, int n_post, int nwords)
{
    __shared__ uint bits[NW_MAX];
    const int tid = threadIdx.x;
    for (int i = tid; i < nwords; i += P1_BLK) bits[i] = bits_g[i];
    __syncthreads();

    // Physical XCD id (wave-uniform SGPR read). Replica = xcc*2 + parity:
    // each replica is touched by exactly ONE XCD -> L2-local atomics.
    uint xcc = (uint)__builtin_amdgcn_s_getreg(GETREG_XCC_ID);
    float* __restrict__ myrep =
        rep + (size_t)(((xcc & 7u) << 1) | (blockIdx.x & 1u)) * (size_t)n_post;

    const int stride = gridDim.x * P1_BLK;
    for (int v = blockIdx.x * P1_BLK + tid; v < n_vec; v += stride) {
        vint4   ia = __builtin_nontemporal_load(&idx4[2 * v]);
        vint4   ib = __builtin_nontemporal_load(&idx4[2 * v + 1]);
        vfloat4 wv = __builtin_nontemporal_load(&w4[v]);

        const int   posts[4] = {ia.x, ia.z, ib.x, ib.z};
        const int   pres[4]  = {ia.y, ia.w, ib.y, ib.w};
        const float wsv[4]   = {wv.x, wv.y, wv.z, wv.w};

        #pragma unroll
        for (int j = 0; j < 4; ++j) {
            uint pre = (uint)pres[j];
            if ((bits[pre >> 5] >> (pre & 31u)) & 1u)
                atomicAdd(&myrep[(uint)posts[j]], wsv[j]);   // fire-and-forget
        }
    }
}

__global__ __launch_bounds__(256) void p3_merge_rep(
    const float* __restrict__ rep, float* __restrict__ out, int n_post)
{
    int g = blockIdx.x * 256 + threadIdx.x;
    if (g < n_post) {
        float acc = 0.f;
        const float* p = rep + g;
        #pragma unroll
        for (int k = 0; k < REP; ++k) acc += p[(size_t)k * (size_t)n_post];
        out[g] = acc;
    }
}

// Fallback: known-good direct device-atomic kernel (727 us).
__global__ __launch_bounds__(256) void syn_scatter_direct(
    const int* __restrict__ act, const vint4* __restrict__ idx4,
    const vfloat4* __restrict__ w4, float* __restrict__ out, int n_vec)
{
    int t = blockIdx.x * blockDim.x + threadIdx.x;
    if (t >= n_vec) return;
    vint4 ia = idx4[2 * t], ib = idx4[2 * t + 1];
    vfloat4 wv = w4[t];
    if (act[ia.y] > 0) atomicAdd(&out[ia.x], wv.x);
    if (act[ia.w] > 0) atomicAdd(&out[ia.z], wv.y);
    if (act[ib.y] > 0) atomicAdd(&out[ib.x], wv.z);
    if (act[ib.w] > 0) atomicAdd(&out[ib.z], wv.w);
}

extern "C" void kernel_launch(void* const* d_in, const int* in_sizes, int n_in,
                              void* d_out, int out_size, void* d_ws, size_t ws_size,
                              hipStream_t stream) {
    const int*   act     = (const int*)d_in[0];    // (1, n_src) int32
    const int*   indices = (const int*)d_in[1];    // (n_syn, 2) int32
    const float* weights = (const float*)d_in[2];  // (n_syn,) float32

    const int n_src  = in_sizes[0];
    const int n_syn  = in_sizes[2];
    const int n_post = out_size;
    const int n_vec  = n_syn / 4;

    const int nwords = (n_src + 31) >> 5;

    const size_t rep_bytes = (size_t)REP * (size_t)n_post * sizeof(float);
    const size_t need      = 4096 + rep_bytes;

    bool ok = (n_syn % 4 == 0) && (nwords <= NW_MAX) && (ws_size >= need);

    if (!ok) {
        (void)hipMemsetAsync(d_out, 0, (size_t)n_post * sizeof(float), stream);
        const int grid = (n_vec + 255) / 256;
        syn_scatter_direct<<<grid, 256, 0, stream>>>(
            act, (const vint4*)indices, (const vfloat4*)weights, (float*)d_out, n_vec);
        return;
    }

    uint*  bits_g = (uint*)d_ws;
    float* rep    = (float*)((char*)d_ws + 4096);

    (void)hipMemsetAsync(rep, 0, rep_bytes, stream);
    p0_bitmask<<<(nwords + 255) / 256, 256, 0, stream>>>(act, bits_g, n_src);

    int grid = (n_vec + P1_BLK - 1) / P1_BLK;
    if (grid > P1_GRID_CAP) grid = P1_GRID_CAP;
    p1_scatter_rep<<<grid, P1_BLK, 0, stream>>>(
        bits_g, (const vint4*)indices, (const vfloat4*)weights,
        rep, n_vec, n_post, nwords);

    p3_merge_rep<<<(n_post + 255) / 256, 256, 0, stream>>>(
        rep, (float*)d_out, n_post);
}